// Round 1
// baseline (632.192 us; speedup 1.0000x reference)
//
#include <hip/hip_runtime.h>
#include <math.h>

// Problem constants
#define B 64
#define D 2048
#define H 4096
#define NSEED 50000
#define KTOP 50
#define NCHUNKS 64          // topk chunks per row
#define CHUNK_SZ 782        // ceil(50000/64)

// ws layout (float offsets) — total ~5.06M floats ≈ 20.3 MB
#define WS_LOGITS   0                         // 64*50000 = 3,200,000
#define WS_H        3200000                   // 64*4096  = 262,144
#define WS_Q2       (WS_H + B*H)              // 64*2048  = 131,072
#define WS_PART     (WS_Q2 + B*D)             // 1,048,576 (reused by both MLP gemms)
#define WS_CVAL     (WS_PART + 1048576)       // 64*64*50 = 204,800
#define WS_CIDX     (WS_CVAL + 204800)        // 204,800 (ints)
#define WS_CM       (WS_CIDX + 204800)        // 4096
#define WS_CS       (WS_CM + 4096)            // 4096
#define WS_RM       (WS_CS + 4096)            // 64
#define WS_RS       (WS_RM + 64)              // 64
#define WS_TIDX     (WS_RS + 64)              // 3200 (ints)

// ---------------------------------------------------------------------------
// MLP GEMM: C_partial[kc][64][N] = A[64][K_chunk] @ W[K_chunk][N]
// grid = nBlocks * nchunks, 256 threads. Tile: 64m x 64n, KS=32.
// Thread micro-tile: 8m x 2n.
// ---------------------------------------------------------------------------
__global__ __launch_bounds__(256) void gemm64_kernel(
    const float* __restrict__ A, const float* __restrict__ W,
    float* __restrict__ part, int K, int N, int kcK, int nBlocks)
{
    __shared__ float As[32][68];   // [k][m], padded
    __shared__ float Bs[32][68];   // [k][n], padded

    const int tid = threadIdx.x;
    const int nb = blockIdx.x % nBlocks;
    const int kc = blockIdx.x / nBlocks;
    const int kbeg = kc * kcK;

    const int tidm = tid >> 5;          // 0..7
    const int tidn = tid & 31;          // 0..31
    const int m0 = tidm * 8;
    const int n0g = nb * 64 + tidn * 2;

    float acc[8][2];
#pragma unroll
    for (int i = 0; i < 8; ++i) { acc[i][0] = 0.f; acc[i][1] = 0.f; }

    for (int k0 = kbeg; k0 < kbeg + kcK; k0 += 32) {
        __syncthreads();
#pragma unroll
        for (int i = 0; i < 2; ++i) {
            int q = tid + i * 256;                 // 0..511
            int row = q >> 3, c = q & 7;           // A tile: 64 rows x 32 k
            float4 va = *(const float4*)(A + (size_t)row * K + k0 + c * 4);
            As[c * 4 + 0][row] = va.x; As[c * 4 + 1][row] = va.y;
            As[c * 4 + 2][row] = va.z; As[c * 4 + 3][row] = va.w;
            int wr = q >> 4, wc = q & 15;          // W tile: 32 k x 64 n
            float4 vb = *(const float4*)(W + (size_t)(k0 + wr) * N + nb * 64 + wc * 4);
            *(float4*)&Bs[wr][wc * 4] = vb;
        }
        __syncthreads();
#pragma unroll
        for (int kk = 0; kk < 32; ++kk) {
            float4 a0 = *(const float4*)&As[kk][m0];
            float4 a1 = *(const float4*)&As[kk][m0 + 4];
            float2 b = *(const float2*)&Bs[kk][tidn * 2];
            float av[8] = {a0.x, a0.y, a0.z, a0.w, a1.x, a1.y, a1.z, a1.w};
#pragma unroll
            for (int i = 0; i < 8; ++i) {
                acc[i][0] += av[i] * b.x;
                acc[i][1] += av[i] * b.y;
            }
        }
    }
#pragma unroll
    for (int i = 0; i < 8; ++i) {
        float2 v; v.x = acc[i][0]; v.y = acc[i][1];
        *(float2*)(part + (size_t)(kc * B + m0 + i) * N + n0g) = v;
    }
}

// Reduce K-chunk partials + bias (+ optional exact GELU)
__global__ void mlp_reduce_kernel(const float* __restrict__ part,
                                  const float* __restrict__ bias,
                                  float* __restrict__ out, int N, int nchunks, int gelu)
{
    int e = blockIdx.x * 256 + threadIdx.x;   // over B*N
    int b = e / N, j = e - b * N;
    float s = bias[j];
    for (int c = 0; c < nchunks; ++c)
        s += part[(size_t)(c * B + b) * N + j];
    if (gelu)
        s = 0.5f * s * (1.0f + erff(s * 0.70710678118654752f));
    out[e] = s;
}

// int64-layout hedge for vritti_types (values 0..4 -> high words all zero)
__device__ __forceinline__ bool types_is_i64(const int* t)
{
    int acc = 0;
#pragma unroll
    for (int j = 0; j < 16; ++j) acc |= t[2 * j + 1];
    return acc == 0;
}

// ---------------------------------------------------------------------------
// sims: logits[64][50000] = (q2 @ seed^T) * gate(karma) + vbias[type]
// grid = 196, 256 threads. Tile 64m x 256n, KS=16. Micro 8m x 8n.
// ---------------------------------------------------------------------------
__global__ __launch_bounds__(256) void sims_kernel(
    const float* __restrict__ q2, const float* __restrict__ seed,
    const float* __restrict__ karma, const int* __restrict__ types,
    const float* __restrict__ vbias, float* __restrict__ logits)
{
    __shared__ float As[16][68];     // [k][m]
    __shared__ float Bs[16][260];    // [k][n]

    const int tid = threadIdx.x;
    const int nbase = blockIdx.x * 256;
    const int tidm = tid >> 5;       // 0..7
    const int tidn = tid & 31;       // 0..31
    const int m0 = tidm * 8;
    const int n0 = tidn * 8;

    float acc[8][8];
#pragma unroll
    for (int i = 0; i < 8; ++i)
#pragma unroll
        for (int j = 0; j < 8; ++j) acc[i][j] = 0.f;

    const int arow = tid >> 2, ac = tid & 3;

    for (int k0 = 0; k0 < D; k0 += 16) {
        __syncthreads();
        {   // A tile: 64 rows x 16 k (one float4/thread)
            float4 va = *(const float4*)(q2 + (size_t)arow * D + k0 + ac * 4);
            As[ac * 4 + 0][arow] = va.x; As[ac * 4 + 1][arow] = va.y;
            As[ac * 4 + 2][arow] = va.z; As[ac * 4 + 3][arow] = va.w;
        }
#pragma unroll
        for (int i = 0; i < 4; ++i) {   // B tile: 256 n x 16 k
            int q = tid + i * 256;
            int n = q >> 2, c = q & 3;
            int ng = nbase + n;
            float4 vb = make_float4(0.f, 0.f, 0.f, 0.f);
            if (ng < NSEED)
                vb = *(const float4*)(seed + (size_t)ng * D + k0 + c * 4);
            Bs[c * 4 + 0][n] = vb.x; Bs[c * 4 + 1][n] = vb.y;
            Bs[c * 4 + 2][n] = vb.z; Bs[c * 4 + 3][n] = vb.w;
        }
        __syncthreads();
#pragma unroll
        for (int kk = 0; kk < 16; ++kk) {
            float4 a0 = *(const float4*)&As[kk][m0];
            float4 a1 = *(const float4*)&As[kk][m0 + 4];
            float4 b0 = *(const float4*)&Bs[kk][n0];
            float4 b1 = *(const float4*)&Bs[kk][n0 + 4];
            float av[8] = {a0.x, a0.y, a0.z, a0.w, a1.x, a1.y, a1.z, a1.w};
            float bv[8] = {b0.x, b0.y, b0.z, b0.w, b1.x, b1.y, b1.z, b1.w};
#pragma unroll
            for (int i = 0; i < 8; ++i)
#pragma unroll
                for (int j = 0; j < 8; ++j)
                    acc[i][j] += av[i] * bv[j];
        }
    }

    const int ng0 = nbase + n0;
    if (ng0 < NSEED) {   // per-thread all-in or all-out (50000 % 8 == 0)
        const bool i64 = types_is_i64(types);
        float gate[8], bvv[8];
#pragma unroll
        for (int j = 0; j < 8; ++j) {
            float ka = karma[ng0 + j];
            gate[j] = 1.0f / (1.0f + expf(-(ka + 0.3f) * 10.0f));
            int ty = i64 ? types[2 * (ng0 + j)] : types[ng0 + j];
            bvv[j] = vbias[ty];
        }
#pragma unroll
        for (int i = 0; i < 8; ++i) {
            float4 o0, o1;
            o0.x = acc[i][0] * gate[0] + bvv[0];
            o0.y = acc[i][1] * gate[1] + bvv[1];
            o0.z = acc[i][2] * gate[2] + bvv[2];
            o0.w = acc[i][3] * gate[3] + bvv[3];
            o1.x = acc[i][4] * gate[4] + bvv[4];
            o1.y = acc[i][5] * gate[5] + bvv[5];
            o1.z = acc[i][6] * gate[6] + bvv[6];
            o1.w = acc[i][7] * gate[7] + bvv[7];
            float* dst = logits + (size_t)(m0 + i) * NSEED + ng0;
            *(float4*)dst = o0;
            *(float4*)(dst + 4) = o1;
        }
    }
}

// ---------------------------------------------------------------------------
// Per-(row,chunk): online softmax partial (m,s) + exact chunk top-50.
// grid = 64 rows * 64 chunks, 64 threads (1 wave, no __syncthreads).
// Tie-break: lower index first (matches jax.lax.top_k).
// ---------------------------------------------------------------------------
__global__ __launch_bounds__(64) void chunk_topk_kernel(
    const float* __restrict__ logits,
    float* __restrict__ chunk_m, float* __restrict__ chunk_s,
    float* __restrict__ cand_val, int* __restrict__ cand_idx)
{
    const int bid = blockIdx.x;
    const int row = bid >> 6, chunk = bid & 63;
    const int start = chunk * CHUNK_SZ;
    const int end = min(start + CHUNK_SZ, NSEED);
    const int lane = threadIdx.x;
    const float* Lrow = logits + (size_t)row * NSEED;

    float v[13];
#pragma unroll
    for (int j = 0; j < 13; ++j) {
        int e = start + lane + j * 64;
        v[j] = (e < end) ? Lrow[e] : -INFINITY;
    }

    // online (m, s) partial: s = sum exp(2*(l - m))
    float m = v[0];
#pragma unroll
    for (int j = 1; j < 13; ++j) m = fmaxf(m, v[j]);
    float s = 0.f;
#pragma unroll
    for (int j = 0; j < 13; ++j) s += expf(2.f * (v[j] - m));   // exp(-inf)=0
#pragma unroll
    for (int d = 1; d < 64; d <<= 1) {
        float mo = __shfl_xor(m, d);
        float so = __shfl_xor(s, d);
        float nm = fmaxf(m, mo);
        s = s * expf(2.f * (m - nm)) + so * expf(2.f * (mo - nm));
        m = nm;
    }
    if (lane == 0) { chunk_m[bid] = m; chunk_s[bid] = s; }

    // chunk top-50 via 50 wave-argmax iterations
    for (int it = 0; it < KTOP; ++it) {
        float bv = v[0]; int bj = 0;
#pragma unroll
        for (int j = 1; j < 13; ++j)
            if (v[j] > bv) { bv = v[j]; bj = j; }   // strict > keeps lowest idx
        int bi = start + lane + bj * 64;
#pragma unroll
        for (int d = 1; d < 64; d <<= 1) {
            float ov = __shfl_xor(bv, d);
            int oi = __shfl_xor(bi, d);
            if (ov > bv || (ov == bv && oi < bi)) { bv = ov; bi = oi; }
        }
        if (lane == 0) {
            cand_val[bid * KTOP + it] = bv;
            cand_idx[bid * KTOP + it] = bi;
        }
#pragma unroll
        for (int j = 0; j < 13; ++j)
            if (start + lane + j * 64 == bi) v[j] = -INFINITY;
    }
}

// ---------------------------------------------------------------------------
// Per-row merge: 64 (m,s) partials -> (M, 1/S); 3200 candidates -> top-50.
// grid = 64, 256 threads. Writes float indices to d_out + int copy to ws.
// ---------------------------------------------------------------------------
__global__ __launch_bounds__(256) void merge_topk_kernel(
    const float* __restrict__ chunk_m, const float* __restrict__ chunk_s,
    const float* __restrict__ cand_val, const int* __restrict__ cand_idx,
    float* __restrict__ row_M, float* __restrict__ row_rS,
    float* __restrict__ out_idx_f, int* __restrict__ topk_idx)
{
    const int row = blockIdx.x;
    const int tid = threadIdx.x;
    const int lane = tid & 63, wave = tid >> 6;
    __shared__ float rv[4];
    __shared__ int ri[4];

    if (wave == 0) {   // softmax stats merge (one wave)
        float m = chunk_m[row * 64 + lane];
        float s = chunk_s[row * 64 + lane];
#pragma unroll
        for (int d = 1; d < 64; d <<= 1) {
            float mo = __shfl_xor(m, d);
            float so = __shfl_xor(s, d);
            float nm = fmaxf(m, mo);
            s = s * expf(2.f * (m - nm)) + so * expf(2.f * (mo - nm));
            m = nm;
        }
        if (lane == 0) { row_M[row] = m; row_rS[row] = 1.0f / s; }
    }

    float v[13]; int ix[13];
#pragma unroll
    for (int j = 0; j < 13; ++j) {
        int e = tid + j * 256;
        if (e < NCHUNKS * KTOP) {
            v[j] = cand_val[row * (NCHUNKS * KTOP) + e];
            ix[j] = cand_idx[row * (NCHUNKS * KTOP) + e];
        } else { v[j] = -INFINITY; ix[j] = 0x7fffffff; }
    }

    for (int it = 0; it < KTOP; ++it) {
        float bv = v[0]; int bi = ix[0];
#pragma unroll
        for (int j = 1; j < 13; ++j)
            if (v[j] > bv || (v[j] == bv && ix[j] < bi)) { bv = v[j]; bi = ix[j]; }
#pragma unroll
        for (int d = 1; d < 64; d <<= 1) {
            float ov = __shfl_xor(bv, d);
            int oi = __shfl_xor(bi, d);
            if (ov > bv || (ov == bv && oi < bi)) { bv = ov; bi = oi; }
        }
        if (lane == 0) { rv[wave] = bv; ri[wave] = bi; }
        __syncthreads();
        float wv = rv[0]; int wi = ri[0];
#pragma unroll
        for (int w = 1; w < 4; ++w)
            if (rv[w] > wv || (rv[w] == wv && ri[w] < wi)) { wv = rv[w]; wi = ri[w]; }
        __syncthreads();
        if (tid == 0) {
            out_idx_f[row * KTOP + it] = (float)wi;
            topk_idx[row * KTOP + it] = wi;
        }
#pragma unroll
        for (int j = 0; j < 13; ++j)
            if (ix[j] == wi) v[j] = -INFINITY;
    }
}

// attention weights: w = exp(2*(l - M)) / S, vectorized float4
__global__ void weights_kernel(const float* __restrict__ logits,
                               const float* __restrict__ row_M,
                               const float* __restrict__ row_rS,
                               float* __restrict__ attn)
{
    const int row = blockIdx.y;
    const int f = blockIdx.x * 256 + threadIdx.x;
    if (f >= NSEED / 4) return;
    const float M = row_M[row], rS = row_rS[row];
    float4 l = ((const float4*)(logits + (size_t)row * NSEED))[f];
    float4 w;
    w.x = expf(2.f * (l.x - M)) * rS;
    w.y = expf(2.f * (l.y - M)) * rS;
    w.z = expf(2.f * (l.z - M)) * rS;
    w.w = expf(2.f * (l.w - M)) * rS;
    ((float4*)(attn + (size_t)row * NSEED))[f] = w;
}

// chitta gather: 2048 floats per (row,k)
__global__ void gather_kernel(const float* __restrict__ seed,
                              const int* __restrict__ topk_idx,
                              float* __restrict__ chitta)
{
    const int k = blockIdx.x, row = blockIdx.y;
    const int idx = topk_idx[row * KTOP + k];
    const float4* src = (const float4*)(seed + (size_t)idx * D);
    float4* dst = (float4*)(chitta + (size_t)(row * KTOP + k) * D);
#pragma unroll
    for (int j = 0; j < 2; ++j)
        dst[threadIdx.x + j * 256] = src[threadIdx.x + j * 256];
}

extern "C" void kernel_launch(void* const* d_in, const int* in_sizes, int n_in,
                              void* d_out, int out_size, void* d_ws, size_t ws_size,
                              hipStream_t stream)
{
    const float* query = (const float*)d_in[0];
    const int*   types = (const int*)d_in[1];
    const float* seed  = (const float*)d_in[2];
    const float* karma = (const float*)d_in[3];
    const float* vbias = (const float*)d_in[4];
    const float* W1    = (const float*)d_in[5];
    const float* b1    = (const float*)d_in[6];
    const float* W2    = (const float*)d_in[7];
    const float* b2    = (const float*)d_in[8];

    float* ws = (float*)d_ws;
    float* logits = ws + WS_LOGITS;
    float* h      = ws + WS_H;
    float* q2     = ws + WS_Q2;
    float* part   = ws + WS_PART;
    float* cval   = ws + WS_CVAL;
    int*   cidx   = (int*)(ws + WS_CIDX);
    float* cm     = ws + WS_CM;
    float* cs     = ws + WS_CS;
    float* rM     = ws + WS_RM;
    float* rS     = ws + WS_RS;
    int*   tidx   = (int*)(ws + WS_TIDX);

    float* outv   = (float*)d_out;
    float* chitta = outv;                                   // [64][50][2048]
    float* attn   = outv + (size_t)B * KTOP * D;            // [64][50000]
    float* oidxf  = attn + (size_t)B * NSEED;               // [64][50] as float

    // MLP layer 1: 64 n-blocks x 4 k-chunks (K chunk = 512)
    gemm64_kernel<<<256, 256, 0, stream>>>(query, W1, part, D, H, 512, H / 64);
    mlp_reduce_kernel<<<(B * H) / 256, 256, 0, stream>>>(part, b1, h, H, 4, 1);
    // MLP layer 2: 32 n-blocks x 8 k-chunks (K chunk = 512)
    gemm64_kernel<<<256, 256, 0, stream>>>(h, W2, part, H, D, 512, D / 64);
    mlp_reduce_kernel<<<(B * D) / 256, 256, 0, stream>>>(part, b2, q2, D, 8, 0);
    // similarity + gate + bias -> logits
    sims_kernel<<<(NSEED + 255) / 256, 256, 0, stream>>>(q2, seed, karma, types, vbias, logits);
    // per-chunk stats + top-50 candidates
    chunk_topk_kernel<<<B * NCHUNKS, 64, 0, stream>>>(logits, cm, cs, cval, cidx);
    // per-row merge -> (M, 1/S) + final sorted top-50 indices
    merge_topk_kernel<<<B, 256, 0, stream>>>(cm, cs, cval, cidx, rM, rS, oidxf, tidx);
    // full attention weights
    weights_kernel<<<dim3((NSEED / 4 + 255) / 256, B), 256, 0, stream>>>(logits, rM, rS, attn);
    // retrieved embeddings
    gather_kernel<<<dim3(KTOP, B), 256, 0, stream>>>(seed, tidx, chitta);
}